// Round 2
// baseline (1147.134 us; speedup 1.0000x reference)
//
#include <hip/hip_runtime.h>
#include <cstdint>

#define T_SEQ 2048
#define C_DIM 768
#define C3    2304
#define NH    12
#define HD    64

typedef float f32x4 __attribute__((ext_vector_type(4)));
typedef short s16x8 __attribute__((ext_vector_type(8)));
typedef short s16x4 __attribute__((ext_vector_type(4)));

__device__ __forceinline__ unsigned short bf16_rtne(float x) {
    union { float f; unsigned u; } v; v.f = x;
    unsigned r = (v.u + 0x7FFFu + ((v.u >> 16) & 1u)) >> 16;
    return (unsigned short)r;
}
__device__ __forceinline__ float bf16_tof(unsigned short h) {
    union { float f; unsigned u; } v; v.u = ((unsigned)h) << 16;
    return v.f;
}

// ---------------------------------------------------------------------------
// Split-bf16 MFMA GEMM: C[M,N] = A[M,K] @ Bw[N,K]^T + bias[N]
// fp32 in / fp32 out; internally a = a_hi + a_lo (bf16 pair), 3-term MFMA:
// acc += Ahi*Bhi + Ahi*Blo + Alo*Bhi  (rel err ~2^-16).
// Block tile 128 x (NF*32), 256 threads = 4 waves (2x2), wave tile 64 x (NF*16).
// 16x16x32 bf16 MFMA. LDS row stride 40 bf16 = 80 B -> 2-way (free) conflicts.
// ---------------------------------------------------------------------------
template<int NF>
__global__ __launch_bounds__(256, 2) void gemm_bt_mfma(const float* __restrict__ A,
                                                       const float* __restrict__ Bw,
                                                       const float* __restrict__ bias,
                                                       float* __restrict__ Cout,
                                                       int M, int N, int K)
{
    __shared__ short Ah[128][40];
    __shared__ short Al[128][40];
    __shared__ short Bh[NF * 32][40];
    __shared__ short Bl[NF * 32][40];

    const int t    = threadIdx.x;
    const int w    = t >> 6;
    const int lane = t & 63;
    const int lr   = lane & 15;          // frag row (A) / col (B,D)
    const int lk   = (lane >> 4) * 8;    // frag k offset
    const int lc4  = (lane >> 4) * 4;    // D row offset
    const int m0   = blockIdx.y * 128;
    const int n0   = blockIdx.x * (NF * 32);
    const int wm   = (w >> 1) * 64;
    const int wn   = (w & 1) * (NF * 16);

    f32x4 acc[4][NF];
#pragma unroll
    for (int i = 0; i < 4; ++i)
#pragma unroll
        for (int j = 0; j < NF; ++j) acc[i][j] = (f32x4){0.f, 0.f, 0.f, 0.f};

    for (int kk = 0; kk < K; kk += 32) {
        // ---- stage A tile (128x32) as hi/lo bf16 ----
#pragma unroll
        for (int i = 0; i < 4; ++i) {
            const int c   = t + i * 256;
            const int row = c >> 3;
            const int k4  = (c & 7) * 4;
            const float4 va = *(const float4*)&A[(size_t)(m0 + row) * K + kk + k4];
            unsigned short h0 = bf16_rtne(va.x), h1 = bf16_rtne(va.y),
                           h2 = bf16_rtne(va.z), h3 = bf16_rtne(va.w);
            unsigned short l0 = bf16_rtne(va.x - bf16_tof(h0)),
                           l1 = bf16_rtne(va.y - bf16_tof(h1)),
                           l2 = bf16_rtne(va.z - bf16_tof(h2)),
                           l3 = bf16_rtne(va.w - bf16_tof(h3));
            *(s16x4*)&Ah[row][k4] = (s16x4){(short)h0, (short)h1, (short)h2, (short)h3};
            *(s16x4*)&Al[row][k4] = (s16x4){(short)l0, (short)l1, (short)l2, (short)l3};
        }
        // ---- stage B tile (NF*32 x 32) as hi/lo bf16 ----
#pragma unroll
        for (int i = 0; i < NF; ++i) {
            const int c   = t + i * 256;
            const int row = c >> 3;
            const int k4  = (c & 7) * 4;
            const float4 vb = *(const float4*)&Bw[(size_t)(n0 + row) * K + kk + k4];
            unsigned short h0 = bf16_rtne(vb.x), h1 = bf16_rtne(vb.y),
                           h2 = bf16_rtne(vb.z), h3 = bf16_rtne(vb.w);
            unsigned short l0 = bf16_rtne(vb.x - bf16_tof(h0)),
                           l1 = bf16_rtne(vb.y - bf16_tof(h1)),
                           l2 = bf16_rtne(vb.z - bf16_tof(h2)),
                           l3 = bf16_rtne(vb.w - bf16_tof(h3));
            *(s16x4*)&Bh[row][k4] = (s16x4){(short)h0, (short)h1, (short)h2, (short)h3};
            *(s16x4*)&Bl[row][k4] = (s16x4){(short)l0, (short)l1, (short)l2, (short)l3};
        }
        __syncthreads();

        // ---- fragments + MFMA ----
        s16x8 afh[4], afl[4];
#pragma unroll
        for (int i = 0; i < 4; ++i) {
            afh[i] = *(const s16x8*)&Ah[wm + i * 16 + lr][lk];
            afl[i] = *(const s16x8*)&Al[wm + i * 16 + lr][lk];
        }
#pragma unroll
        for (int j = 0; j < NF; ++j) {
            const s16x8 bfh = *(const s16x8*)&Bh[wn + j * 16 + lr][lk];
            const s16x8 bfl = *(const s16x8*)&Bl[wn + j * 16 + lr][lk];
#pragma unroll
            for (int i = 0; i < 4; ++i) {
                acc[i][j] = __builtin_amdgcn_mfma_f32_16x16x32_bf16(afh[i], bfh, acc[i][j], 0, 0, 0);
                acc[i][j] = __builtin_amdgcn_mfma_f32_16x16x32_bf16(afh[i], bfl, acc[i][j], 0, 0, 0);
                acc[i][j] = __builtin_amdgcn_mfma_f32_16x16x32_bf16(afl[i], bfh, acc[i][j], 0, 0, 0);
            }
        }
        __syncthreads();
    }

    // ---- epilogue: D row=(l>>4)*4+r, col=l&15 (m89-verified) ----
#pragma unroll
    for (int j = 0; j < NF; ++j) {
        const float bj = bias[n0 + wn + j * 16 + lr];
#pragma unroll
        for (int i = 0; i < 4; ++i) {
#pragma unroll
            for (int r = 0; r < 4; ++r) {
                const int row = m0 + wm + i * 16 + lc4 + r;
                Cout[(size_t)row * N + n0 + wn + j * 16 + lr] = acc[i][j][r] + bj;
            }
        }
    }
}

// ---------------------------------------------------------------------------
// Flash attention (causal), fp32 vector — unchanged known-good structure.
// One block = one (b, h, 64-row Q tile); 256 threads as 16x16; 4x4 per thread.
// ---------------------------------------------------------------------------
#define NEG_BIG (-3.402823466e+38f)

__global__ __launch_bounds__(256) void flash_attn(const float* __restrict__ qkv,
                                                  float* __restrict__ y)
{
    __shared__ float Qs [64][68];   // [d][r]  transposed Q, pre-scaled
    __shared__ float KPs[64][68];   // [d][k]  transposed K  /  [k][r] transposed P
    __shared__ float Vs [64][68];   // [k][d]

    const int t  = threadIdx.x;
    const int tr = t >> 4;
    const int tc = t & 15;
    const int qt = gridDim.x - 1 - blockIdx.x;   // big tiles first
    const int bh = blockIdx.y;
    const int b  = bh / NH;
    const int h  = bh % NH;
    const int q0 = qt * 64;

    const size_t baseQ = (size_t)b * T_SEQ * C3 + (size_t)h * HD;
    const size_t baseK = baseQ + C_DIM;
    const size_t baseV = baseQ + 2 * C_DIM;

#pragma unroll
    for (int i = 0; i < 4; ++i) {
        const int lin = t + i * 256;
        const int row = lin >> 4;
        const int c4  = (lin & 15) * 4;
        const float4 v = *(const float4*)&qkv[baseQ + (size_t)(q0 + row) * C3 + c4];
        Qs[c4 + 0][row] = v.x * 0.125f; Qs[c4 + 1][row] = v.y * 0.125f;
        Qs[c4 + 2][row] = v.z * 0.125f; Qs[c4 + 3][row] = v.w * 0.125f;
    }

    float m_run[4], l_run[4], acc[4][4];
#pragma unroll
    for (int i = 0; i < 4; ++i) {
        m_run[i] = NEG_BIG; l_run[i] = 0.0f;
#pragma unroll
        for (int j = 0; j < 4; ++j) acc[i][j] = 0.0f;
    }

    for (int kt = 0; kt <= qt; ++kt) {
        const int k0 = kt * 64;
#pragma unroll
        for (int i = 0; i < 4; ++i) {
            const int lin = t + i * 256;
            const int row = lin >> 4;
            const int c4  = (lin & 15) * 4;
            const float4 kv = *(const float4*)&qkv[baseK + (size_t)(k0 + row) * C3 + c4];
            KPs[c4 + 0][row] = kv.x; KPs[c4 + 1][row] = kv.y;
            KPs[c4 + 2][row] = kv.z; KPs[c4 + 3][row] = kv.w;
            const float4 vv = *(const float4*)&qkv[baseV + (size_t)(k0 + row) * C3 + c4];
            *(float4*)&Vs[row][c4] = vv;
        }
        __syncthreads();

        float s[4][4];
#pragma unroll
        for (int i = 0; i < 4; ++i)
#pragma unroll
            for (int j = 0; j < 4; ++j) s[i][j] = 0.0f;
#pragma unroll 8
        for (int d = 0; d < 64; ++d) {
            const float4 a  = *(const float4*)&Qs[d][tr * 4];
            const float4 kb = *(const float4*)&KPs[d][tc * 4];
            s[0][0] += a.x * kb.x; s[0][1] += a.x * kb.y; s[0][2] += a.x * kb.z; s[0][3] += a.x * kb.w;
            s[1][0] += a.y * kb.x; s[1][1] += a.y * kb.y; s[1][2] += a.y * kb.z; s[1][3] += a.y * kb.w;
            s[2][0] += a.z * kb.x; s[2][1] += a.z * kb.y; s[2][2] += a.z * kb.z; s[2][3] += a.z * kb.w;
            s[3][0] += a.w * kb.x; s[3][1] += a.w * kb.y; s[3][2] += a.w * kb.z; s[3][3] += a.w * kb.w;
        }

        if (kt == qt) {
#pragma unroll
            for (int i = 0; i < 4; ++i)
#pragma unroll
                for (int j = 0; j < 4; ++j)
                    if (tc * 4 + j > tr * 4 + i) s[i][j] = NEG_BIG;
        }

        float p[4][4];
#pragma unroll
        for (int i = 0; i < 4; ++i) {
            float mt = fmaxf(fmaxf(s[i][0], s[i][1]), fmaxf(s[i][2], s[i][3]));
            mt = fmaxf(mt, __shfl_xor(mt, 1));
            mt = fmaxf(mt, __shfl_xor(mt, 2));
            mt = fmaxf(mt, __shfl_xor(mt, 4));
            mt = fmaxf(mt, __shfl_xor(mt, 8));
            const float mn    = fmaxf(m_run[i], mt);
            const float alpha = __expf(m_run[i] - mn);
            m_run[i] = mn;
            float ls = 0.0f;
#pragma unroll
            for (int j = 0; j < 4; ++j) {
                p[i][j] = __expf(s[i][j] - mn);
                ls += p[i][j];
            }
            ls += __shfl_xor(ls, 1);
            ls += __shfl_xor(ls, 2);
            ls += __shfl_xor(ls, 4);
            ls += __shfl_xor(ls, 8);
            l_run[i] = l_run[i] * alpha + ls;
#pragma unroll
            for (int j = 0; j < 4; ++j) acc[i][j] *= alpha;
        }

        __syncthreads();

#pragma unroll
        for (int j = 0; j < 4; ++j) {
            const float4 wv = {p[0][j], p[1][j], p[2][j], p[3][j]};
            *(float4*)&KPs[tc * 4 + j][tr * 4] = wv;
        }
#pragma unroll 8
        for (int k = 0; k < 64; ++k) {
            const float4 pp = *(const float4*)&KPs[k][tr * 4];
            const float4 vv = *(const float4*)&Vs[k][tc * 4];
            acc[0][0] += pp.x * vv.x; acc[0][1] += pp.x * vv.y; acc[0][2] += pp.x * vv.z; acc[0][3] += pp.x * vv.w;
            acc[1][0] += pp.y * vv.x; acc[1][1] += pp.y * vv.y; acc[1][2] += pp.y * vv.z; acc[1][3] += pp.y * vv.w;
            acc[2][0] += pp.z * vv.x; acc[2][1] += pp.z * vv.y; acc[2][2] += pp.z * vv.z; acc[2][3] += pp.z * vv.w;
            acc[3][0] += pp.w * vv.x; acc[3][1] += pp.w * vv.y; acc[3][2] += pp.w * vv.z; acc[3][3] += pp.w * vv.w;
        }
        __syncthreads();
    }

#pragma unroll
    for (int i = 0; i < 4; ++i) {
        const float inv = 1.0f / l_run[i];
        const float4 o = {acc[i][0] * inv, acc[i][1] * inv, acc[i][2] * inv, acc[i][3] * inv};
        *(float4*)&y[((size_t)b * T_SEQ + q0 + tr * 4 + i) * C_DIM + h * HD + tc * 4] = o;
    }
}

// ---------------------------------------------------------------------------
extern "C" void kernel_launch(void* const* d_in, const int* in_sizes, int n_in,
                              void* d_out, int out_size, void* d_ws, size_t ws_size,
                              hipStream_t stream)
{
    (void)in_sizes; (void)n_in; (void)out_size; (void)ws_size;
    const float* x      = (const float*)d_in[0];
    const float* W_attn = (const float*)d_in[1];
    const float* b_attn = (const float*)d_in[2];
    const float* W_proj = (const float*)d_in[3];
    const float* b_proj = (const float*)d_in[4];
    float* out = (float*)d_out;

    float* qkv = (float*)d_ws;                          // [8192, 2304]
    float* y   = qkv + (size_t)8192 * C3;               // [8192, 768]

    // qkv = x @ W_attn^T + b_attn   (block tile 128x256)
    gemm_bt_mfma<8><<<dim3(C3 / 256, 8192 / 128), 256, 0, stream>>>(x, W_attn, b_attn, qkv,
                                                                    8192, C3, C_DIM);
    // flash attention -> y [B,T,C]
    flash_attn<<<dim3(T_SEQ / 64, 4 * NH), 256, 0, stream>>>(qkv, y);
    // out = y @ W_proj^T + b_proj   (block tile 128x128)
    gemm_bt_mfma<4><<<dim3(C_DIM / 128, 8192 / 128), 256, 0, stream>>>(y, W_proj, b_proj, out,
                                                                       8192, C_DIM, C_DIM);
}

// Round 3
// 612.188 us; speedup vs baseline: 1.8738x; 1.8738x over previous
//
#include <hip/hip_runtime.h>
#include <cstdint>

#define T_SEQ 2048
#define C_DIM 768
#define C3    2304
#define NH    12
#define HD    64

typedef float f32x4 __attribute__((ext_vector_type(4)));
typedef short s16x8 __attribute__((ext_vector_type(8)));
typedef short s16x4 __attribute__((ext_vector_type(4)));

__device__ __forceinline__ unsigned short bf16_rtne(float x) {
    union { float f; unsigned u; } v; v.f = x;
    unsigned r = (v.u + 0x7FFFu + ((v.u >> 16) & 1u)) >> 16;
    return (unsigned short)r;
}
__device__ __forceinline__ float bf16_tof(unsigned short h) {
    union { float f; unsigned u; } v; v.u = ((unsigned)h) << 16;
    return v.f;
}

// ---------------------------------------------------------------------------
// Split-bf16 MFMA GEMM: C[M,N] = A[M,K] @ Bw[N,K]^T + bias[N]  (unchanged,
// known-good: 3-term split, 128 x (NF*32) tile, 4 waves, 16x16x32 bf16 MFMA)
// ---------------------------------------------------------------------------
template<int NF>
__global__ __launch_bounds__(256, 2) void gemm_bt_mfma(const float* __restrict__ A,
                                                       const float* __restrict__ Bw,
                                                       const float* __restrict__ bias,
                                                       float* __restrict__ Cout,
                                                       int M, int N, int K)
{
    __shared__ short Ah[128][40];
    __shared__ short Al[128][40];
    __shared__ short Bh[NF * 32][40];
    __shared__ short Bl[NF * 32][40];

    const int t    = threadIdx.x;
    const int w    = t >> 6;
    const int lane = t & 63;
    const int lr   = lane & 15;
    const int lk   = (lane >> 4) * 8;
    const int lc4  = (lane >> 4) * 4;
    const int m0   = blockIdx.y * 128;
    const int n0   = blockIdx.x * (NF * 32);
    const int wm   = (w >> 1) * 64;
    const int wn   = (w & 1) * (NF * 16);

    f32x4 acc[4][NF];
#pragma unroll
    for (int i = 0; i < 4; ++i)
#pragma unroll
        for (int j = 0; j < NF; ++j) acc[i][j] = (f32x4){0.f, 0.f, 0.f, 0.f};

    for (int kk = 0; kk < K; kk += 32) {
#pragma unroll
        for (int i = 0; i < 4; ++i) {
            const int c   = t + i * 256;
            const int row = c >> 3;
            const int k4  = (c & 7) * 4;
            const float4 va = *(const float4*)&A[(size_t)(m0 + row) * K + kk + k4];
            unsigned short h0 = bf16_rtne(va.x), h1 = bf16_rtne(va.y),
                           h2 = bf16_rtne(va.z), h3 = bf16_rtne(va.w);
            unsigned short l0 = bf16_rtne(va.x - bf16_tof(h0)),
                           l1 = bf16_rtne(va.y - bf16_tof(h1)),
                           l2 = bf16_rtne(va.z - bf16_tof(h2)),
                           l3 = bf16_rtne(va.w - bf16_tof(h3));
            *(s16x4*)&Ah[row][k4] = (s16x4){(short)h0, (short)h1, (short)h2, (short)h3};
            *(s16x4*)&Al[row][k4] = (s16x4){(short)l0, (short)l1, (short)l2, (short)l3};
        }
#pragma unroll
        for (int i = 0; i < NF; ++i) {
            const int c   = t + i * 256;
            const int row = c >> 3;
            const int k4  = (c & 7) * 4;
            const float4 vb = *(const float4*)&Bw[(size_t)(n0 + row) * K + kk + k4];
            unsigned short h0 = bf16_rtne(vb.x), h1 = bf16_rtne(vb.y),
                           h2 = bf16_rtne(vb.z), h3 = bf16_rtne(vb.w);
            unsigned short l0 = bf16_rtne(vb.x - bf16_tof(h0)),
                           l1 = bf16_rtne(vb.y - bf16_tof(h1)),
                           l2 = bf16_rtne(vb.z - bf16_tof(h2)),
                           l3 = bf16_rtne(vb.w - bf16_tof(h3));
            *(s16x4*)&Bh[row][k4] = (s16x4){(short)h0, (short)h1, (short)h2, (short)h3};
            *(s16x4*)&Bl[row][k4] = (s16x4){(short)l0, (short)l1, (short)l2, (short)l3};
        }
        __syncthreads();

        s16x8 afh[4], afl[4];
#pragma unroll
        for (int i = 0; i < 4; ++i) {
            afh[i] = *(const s16x8*)&Ah[wm + i * 16 + lr][lk];
            afl[i] = *(const s16x8*)&Al[wm + i * 16 + lr][lk];
        }
#pragma unroll
        for (int j = 0; j < NF; ++j) {
            const s16x8 bfh = *(const s16x8*)&Bh[wn + j * 16 + lr][lk];
            const s16x8 bfl = *(const s16x8*)&Bl[wn + j * 16 + lr][lk];
#pragma unroll
            for (int i = 0; i < 4; ++i) {
                acc[i][j] = __builtin_amdgcn_mfma_f32_16x16x32_bf16(afh[i], bfh, acc[i][j], 0, 0, 0);
                acc[i][j] = __builtin_amdgcn_mfma_f32_16x16x32_bf16(afh[i], bfl, acc[i][j], 0, 0, 0);
                acc[i][j] = __builtin_amdgcn_mfma_f32_16x16x32_bf16(afl[i], bfh, acc[i][j], 0, 0, 0);
            }
        }
        __syncthreads();
    }

#pragma unroll
    for (int j = 0; j < NF; ++j) {
        const float bj = bias[n0 + wn + j * 16 + lr];
#pragma unroll
        for (int i = 0; i < 4; ++i) {
#pragma unroll
            for (int r = 0; r < 4; ++r) {
                const int row = m0 + wm + i * 16 + lc4 + r;
                Cout[(size_t)row * N + n0 + wn + j * 16 + lr] = acc[i][j][r] + bj;
            }
        }
    }
}

// ---------------------------------------------------------------------------
// Flash attention (causal), MFMA version.
// One block = (b, h, 64-row Q tile). 256 thr = 4 waves; wave w owns q-strip
// [16w,16w+16).  S^T = K @ Q^T (A=K[k][d] single-bf16, B=Q[q][d] split hi/lo,
// 2-term) -> lane holds one q-column of 16 S values (k = 16*sm+4*g+r).
// Softmax: in-register + shfl_xor(16,32). P[q][k] written with b64 (no
// scatter). PV: A=P[q][k], B=V^T[d][k] (V transposed in 4x4 reg blocks at
// staging). alpha / 1/l broadcast via 64-float LDS buffer (wave-local).
// LDS: 3 x [64][72] bf16 (Q hi/lo overlaid on K/Vt) + 64 f32 = ~28 KB.
// ---------------------------------------------------------------------------
#define NEG_BIG (-3.402823466e+38f)

__global__ __launch_bounds__(256) void flash_attn_mfma(const float* __restrict__ qkv,
                                                       float* __restrict__ y)
{
    __shared__ short U[3][64][72];
    __shared__ float redbuf[64];

    const int t = threadIdx.x;
    const int w = t >> 6;          // wave 0..3
    const int l = t & 63;
    const int c = l & 15;          // frag row / q-col
    const int g = l >> 4;          // lane group 0..3

    const int qt = gridDim.x - 1 - blockIdx.x;   // big tiles first
    const int bh = blockIdx.y;
    const int b  = bh / NH;
    const int h  = bh % NH;
    const int q0 = qt * 64;

    const size_t baseQ = (size_t)b * T_SEQ * C3 + (size_t)h * HD;
    const size_t baseK = baseQ + C_DIM;
    const size_t baseV = baseQ + 2 * C_DIM;

    // ---- stage Q hi/lo (pre-scaled), extract B-frags to regs, then free LDS
    {
        short (*Qh)[72] = U[0];
        short (*Ql)[72] = U[1];
#pragma unroll
        for (int i = 0; i < 4; ++i) {
            const int lin = t + i * 256;
            const int row = lin >> 4;
            const int d4  = (lin & 15) * 4;
            float4 v = *(const float4*)&qkv[baseQ + (size_t)(q0 + row) * C3 + d4];
            v.x *= 0.125f; v.y *= 0.125f; v.z *= 0.125f; v.w *= 0.125f;
            unsigned short h0 = bf16_rtne(v.x), h1 = bf16_rtne(v.y),
                           h2 = bf16_rtne(v.z), h3 = bf16_rtne(v.w);
            *(s16x4*)&Qh[row][d4] = (s16x4){(short)h0, (short)h1, (short)h2, (short)h3};
            *(s16x4*)&Ql[row][d4] = (s16x4){(short)bf16_rtne(v.x - bf16_tof(h0)),
                                            (short)bf16_rtne(v.y - bf16_tof(h1)),
                                            (short)bf16_rtne(v.z - bf16_tof(h2)),
                                            (short)bf16_rtne(v.w - bf16_tof(h3))};
        }
    }
    __syncthreads();
    s16x8 qfh[2], qfl[2];
#pragma unroll
    for (int ds = 0; ds < 2; ++ds) {
        qfh[ds] = *(const s16x8*)&U[0][16 * w + c][ds * 32 + g * 8];
        qfl[ds] = *(const s16x8*)&U[1][16 * w + c][ds * 32 + g * 8];
    }
    __syncthreads();

    f32x4 o[4];
#pragma unroll
    for (int j = 0; j < 4; ++j) o[j] = (f32x4){0.f, 0.f, 0.f, 0.f};
    float m_run = NEG_BIG, l_run = 0.0f;

    short (*Ks)[72] = U[0];
    short (*Vt)[72] = U[1];
    short (*Ps)[72] = U[2];

    for (int kt = 0; kt <= qt; ++kt) {
        const int k0 = kt * 64;

        // ---- stage K (single bf16, natural [k][d]) ----
#pragma unroll
        for (int i = 0; i < 4; ++i) {
            const int lin = t + i * 256;
            const int row = lin >> 4;
            const int d4  = (lin & 15) * 4;
            const float4 v = *(const float4*)&qkv[baseK + (size_t)(k0 + row) * C3 + d4];
            *(s16x4*)&Ks[row][d4] = (s16x4){(short)bf16_rtne(v.x), (short)bf16_rtne(v.y),
                                            (short)bf16_rtne(v.z), (short)bf16_rtne(v.w)};
        }
        // ---- stage V transposed: Vt[d][k], 4x4 register-block transpose ----
        {
            const int d0 = (t & 15) * 4;
            const int kl = (t >> 4) * 4;
            const float4 r0 = *(const float4*)&qkv[baseV + (size_t)(k0 + kl + 0) * C3 + d0];
            const float4 r1 = *(const float4*)&qkv[baseV + (size_t)(k0 + kl + 1) * C3 + d0];
            const float4 r2 = *(const float4*)&qkv[baseV + (size_t)(k0 + kl + 2) * C3 + d0];
            const float4 r3 = *(const float4*)&qkv[baseV + (size_t)(k0 + kl + 3) * C3 + d0];
            const float c0[4] = {r0.x, r1.x, r2.x, r3.x};
            const float c1[4] = {r0.y, r1.y, r2.y, r3.y};
            const float c2[4] = {r0.z, r1.z, r2.z, r3.z};
            const float c3[4] = {r0.w, r1.w, r2.w, r3.w};
            *(s16x4*)&Vt[d0 + 0][kl] = (s16x4){(short)bf16_rtne(c0[0]), (short)bf16_rtne(c0[1]),
                                               (short)bf16_rtne(c0[2]), (short)bf16_rtne(c0[3])};
            *(s16x4*)&Vt[d0 + 1][kl] = (s16x4){(short)bf16_rtne(c1[0]), (short)bf16_rtne(c1[1]),
                                               (short)bf16_rtne(c1[2]), (short)bf16_rtne(c1[3])};
            *(s16x4*)&Vt[d0 + 2][kl] = (s16x4){(short)bf16_rtne(c2[0]), (short)bf16_rtne(c2[1]),
                                               (short)bf16_rtne(c2[2]), (short)bf16_rtne(c2[3])};
            *(s16x4*)&Vt[d0 + 3][kl] = (s16x4){(short)bf16_rtne(c3[0]), (short)bf16_rtne(c3[1]),
                                               (short)bf16_rtne(c3[2]), (short)bf16_rtne(c3[3])};
        }
        __syncthreads();

        // ---- S^T = K @ Q^T : 4 k-subtiles, 2 d-steps, 2 split terms ----
        f32x4 s[4];
#pragma unroll
        for (int sm = 0; sm < 4; ++sm) {
            s[sm] = (f32x4){0.f, 0.f, 0.f, 0.f};
#pragma unroll
            for (int ds = 0; ds < 2; ++ds) {
                const s16x8 kf = *(const s16x8*)&Ks[sm * 16 + c][ds * 32 + g * 8];
                s[sm] = __builtin_amdgcn_mfma_f32_16x16x32_bf16(kf, qfh[ds], s[sm], 0, 0, 0);
                s[sm] = __builtin_amdgcn_mfma_f32_16x16x32_bf16(kf, qfl[ds], s[sm], 0, 0, 0);
            }
        }

        // ---- causal mask (diagonal tile only): k_local > q_local ----
        if (kt == qt) {
            const int ql_ = 16 * w + c;
#pragma unroll
            for (int sm = 0; sm < 4; ++sm)
#pragma unroll
                for (int r = 0; r < 4; ++r)
                    if (16 * sm + 4 * g + r > ql_) s[sm][r] = NEG_BIG;
        }

        // ---- online softmax over the lane's q-column ----
        float mt = NEG_BIG;
#pragma unroll
        for (int sm = 0; sm < 4; ++sm)
#pragma unroll
            for (int r = 0; r < 4; ++r) mt = fmaxf(mt, s[sm][r]);
        mt = fmaxf(mt, __shfl_xor(mt, 16));
        mt = fmaxf(mt, __shfl_xor(mt, 32));
        const float mn    = fmaxf(m_run, mt);
        const float alpha = __expf(m_run - mn);
        m_run = mn;

        float ls = 0.0f;
#pragma unroll
        for (int sm = 0; sm < 4; ++sm)
#pragma unroll
            for (int r = 0; r < 4; ++r) {
                s[sm][r] = __expf(s[sm][r] - mn);
                ls += s[sm][r];
            }
        ls += __shfl_xor(ls, 16);
        ls += __shfl_xor(ls, 32);
        l_run = l_run * alpha + ls;

        if (g == 0) redbuf[16 * w + c] = alpha;   // broadcast alpha to O-layout

        // ---- P[q][k] write (b64, contiguous 4 k per subtile) ----
#pragma unroll
        for (int sm = 0; sm < 4; ++sm)
            *(s16x4*)&Ps[16 * w + c][sm * 16 + g * 4] =
                (s16x4){(short)bf16_rtne(s[sm][0]), (short)bf16_rtne(s[sm][1]),
                        (short)bf16_rtne(s[sm][2]), (short)bf16_rtne(s[sm][3])};

        // ---- rescale O by alpha (per own q-row = 16w + 4g + r) ----
        {
            float av[4];
#pragma unroll
            for (int r = 0; r < 4; ++r) av[r] = redbuf[16 * w + 4 * g + r];
#pragma unroll
            for (int j = 0; j < 4; ++j)
#pragma unroll
                for (int r = 0; r < 4; ++r) o[j][r] *= av[r];
        }

        // ---- PV: O[q][d] += P @ V ----
#pragma unroll
        for (int ks = 0; ks < 2; ++ks) {
            const s16x8 pf = *(const s16x8*)&Ps[16 * w + c][ks * 32 + g * 8];
#pragma unroll
            for (int j = 0; j < 4; ++j) {
                const s16x8 vf = *(const s16x8*)&Vt[16 * j + c][ks * 32 + g * 8];
                o[j] = __builtin_amdgcn_mfma_f32_16x16x32_bf16(pf, vf, o[j], 0, 0, 0);
            }
        }
        __syncthreads();   // before next k-tile overwrites Ks/Vt
    }

    // ---- epilogue: normalize by l and store ----
    if (g == 0) redbuf[16 * w + c] = l_run;
    float linv[4];
#pragma unroll
    for (int r = 0; r < 4; ++r) linv[r] = 1.0f / redbuf[16 * w + 4 * g + r];
#pragma unroll
    for (int j = 0; j < 4; ++j)
#pragma unroll
        for (int r = 0; r < 4; ++r)
            y[((size_t)b * T_SEQ + q0 + 16 * w + 4 * g + r) * C_DIM + h * HD + 16 * j + c] =
                o[j][r] * linv[r];
}

// ---------------------------------------------------------------------------
extern "C" void kernel_launch(void* const* d_in, const int* in_sizes, int n_in,
                              void* d_out, int out_size, void* d_ws, size_t ws_size,
                              hipStream_t stream)
{
    (void)in_sizes; (void)n_in; (void)out_size; (void)ws_size;
    const float* x      = (const float*)d_in[0];
    const float* W_attn = (const float*)d_in[1];
    const float* b_attn = (const float*)d_in[2];
    const float* W_proj = (const float*)d_in[3];
    const float* b_proj = (const float*)d_in[4];
    float* out = (float*)d_out;

    float* qkv = (float*)d_ws;                          // [8192, 2304]
    float* y   = qkv + (size_t)8192 * C3;               // [8192, 768]

    gemm_bt_mfma<8><<<dim3(C3 / 256, 8192 / 128), 256, 0, stream>>>(x, W_attn, b_attn, qkv,
                                                                    8192, C3, C_DIM);
    flash_attn_mfma<<<dim3(T_SEQ / 64, 4 * NH), 256, 0, stream>>>(qkv, y);
    gemm_bt_mfma<4><<<dim3(C_DIM / 128, 8192 / 128), 256, 0, stream>>>(y, W_proj, b_proj, out,
                                                                       8192, C_DIM, C_DIM);
}

// Round 11
// 423.213 us; speedup vs baseline: 2.7105x; 1.4465x over previous
//
#include <hip/hip_runtime.h>
#include <cstdint>

#define T_SEQ 2048
#define C_DIM 768
#define C3    2304
#define NH    12
#define HD    64
#define BT    8192            // B*T

typedef float f32x4 __attribute__((ext_vector_type(4)));
typedef short s16x8 __attribute__((ext_vector_type(8)));
typedef short s16x4 __attribute__((ext_vector_type(4)));

__device__ __forceinline__ unsigned short bf16_rtne(float x) {
    union { float f; unsigned u; } v; v.f = x;
    unsigned r = (v.u + 0x7FFFu + ((v.u >> 16) & 1u)) >> 16;
    return (unsigned short)r;
}
__device__ __forceinline__ float bf16_tof(unsigned short h) {
    union { float f; unsigned u; } v; v.u = ((unsigned)h) << 16;
    return v.f;
}

// ---------------------------------------------------------------------------
// Elementwise fp32 -> (hi, lo) bf16 split. Runs once per input array.
// ---------------------------------------------------------------------------
__global__ __launch_bounds__(256) void split_bf16(const float* __restrict__ in,
                                                  short* __restrict__ hi,
                                                  short* __restrict__ lo, int n4)
{
    for (int i = blockIdx.x * blockDim.x + threadIdx.x; i < n4; i += gridDim.x * blockDim.x) {
        const float4 v = *(const float4*)&in[(size_t)i * 4];
        unsigned short h0 = bf16_rtne(v.x), h1 = bf16_rtne(v.y),
                       h2 = bf16_rtne(v.z), h3 = bf16_rtne(v.w);
        *(s16x4*)&hi[(size_t)i * 4] = (s16x4){(short)h0, (short)h1, (short)h2, (short)h3};
        *(s16x4*)&lo[(size_t)i * 4] = (s16x4){(short)bf16_rtne(v.x - bf16_tof(h0)),
                                              (short)bf16_rtne(v.y - bf16_tof(h1)),
                                              (short)bf16_rtne(v.z - bf16_tof(h2)),
                                              (short)bf16_rtne(v.w - bf16_tof(h3))};
    }
}

// ---------------------------------------------------------------------------
// Split-bf16 MFMA GEMM on pre-split operands.
// C[M,N] = (Ah+Al)[M,K] @ (Bh+Bl)[N,K]^T + bias[N]  (3-term split)
// Tile 128x128, BK=32, 256 thr = 4 waves (2x2), wave tile 64x64 (4x4 frags).
// MODE 0: f32 C out.  MODE 1: QKV epilogue -> Qh/Ql (scaled), K bf16, V^T bf16.
// ---------------------------------------------------------------------------
template<int MODE>
__global__ __launch_bounds__(256, 4) void gemm_bt_bf16(
    const short* __restrict__ Ah_g, const short* __restrict__ Al_g,
    const short* __restrict__ Bh_g, const short* __restrict__ Bl_g,
    const float* __restrict__ bias, float* __restrict__ Cout,
    short* __restrict__ Qh, short* __restrict__ Ql,
    short* __restrict__ Kb, short* __restrict__ Vt,
    int M, int N, int K)
{
    __shared__ short Ah[128][40];
    __shared__ short Al[128][40];
    __shared__ short Bh[128][40];
    __shared__ short Bl[128][40];

    const int t    = threadIdx.x;
    const int w    = t >> 6;
    const int lane = t & 63;
    const int lr   = lane & 15;
    const int g    = lane >> 4;
    const int lk   = g * 8;
    const int m0   = blockIdx.y * 128;
    const int n0   = blockIdx.x * 128;
    const int wm   = (w >> 1) * 64;
    const int wn   = (w & 1) * 64;

    f32x4 acc[4][4];
#pragma unroll
    for (int i = 0; i < 4; ++i)
#pragma unroll
        for (int j = 0; j < 4; ++j) acc[i][j] = (f32x4){0.f, 0.f, 0.f, 0.f};

    for (int kk = 0; kk < K; kk += 32) {
#pragma unroll
        for (int i = 0; i < 2; ++i) {
            const int chunk = t + i * 256;        // 512 x 16B chunks per tile
            const int row   = chunk >> 2;         // 0..127
            const int col8  = (chunk & 3) * 8;    // 0,8,16,24
            const size_t ga = (size_t)(m0 + row) * K + kk + col8;
            const size_t gb = (size_t)(n0 + row) * K + kk + col8;
            *(s16x8*)&Ah[row][col8] = *(const s16x8*)&Ah_g[ga];
            *(s16x8*)&Al[row][col8] = *(const s16x8*)&Al_g[ga];
            *(s16x8*)&Bh[row][col8] = *(const s16x8*)&Bh_g[gb];
            *(s16x8*)&Bl[row][col8] = *(const s16x8*)&Bl_g[gb];
        }
        __syncthreads();

        s16x8 afh[4], afl[4];
#pragma unroll
        for (int i = 0; i < 4; ++i) {
            afh[i] = *(const s16x8*)&Ah[wm + i * 16 + lr][lk];
            afl[i] = *(const s16x8*)&Al[wm + i * 16 + lr][lk];
        }
#pragma unroll
        for (int j = 0; j < 4; ++j) {
            const s16x8 bfh = *(const s16x8*)&Bh[wn + j * 16 + lr][lk];
            const s16x8 bfl = *(const s16x8*)&Bl[wn + j * 16 + lr][lk];
#pragma unroll
            for (int i = 0; i < 4; ++i) {
                acc[i][j] = __builtin_amdgcn_mfma_f32_16x16x32_bf16(afh[i], bfh, acc[i][j], 0, 0, 0);
                acc[i][j] = __builtin_amdgcn_mfma_f32_16x16x32_bf16(afh[i], bfl, acc[i][j], 0, 0, 0);
                acc[i][j] = __builtin_amdgcn_mfma_f32_16x16x32_bf16(afl[i], bfh, acc[i][j], 0, 0, 0);
            }
        }
        __syncthreads();
    }

    if (MODE == 0) {
#pragma unroll
        for (int j = 0; j < 4; ++j) {
            const float bj = bias[n0 + wn + j * 16 + lr];
#pragma unroll
            for (int i = 0; i < 4; ++i)
#pragma unroll
                for (int r = 0; r < 4; ++r) {
                    const int row = m0 + wm + i * 16 + g * 4 + r;
                    Cout[(size_t)row * N + n0 + wn + j * 16 + lr] = acc[i][j][r] + bj;
                }
        }
    } else {
        // QKV epilogue. Whole block is in one region (128-tiles don't straddle 768s).
        const int region = n0 / C_DIM;            // 0=Q, 1=K, 2=V
#pragma unroll
        for (int j = 0; j < 4; ++j) {
            const int n    = n0 + wn + j * 16 + lr;
            const float bj = bias[n];
            const int nr   = n - region * C_DIM;
            const int hh   = nr >> 6;             // head
            const int d    = nr & 63;
#pragma unroll
            for (int i = 0; i < 4; ++i) {
                const int rowb = m0 + wm + i * 16 + g * 4;
                const int b    = rowb >> 11;
                const int tt   = rowb & 2047;
                const size_t hb = (size_t)b * NH + hh;
                if (region == 0) {
#pragma unroll
                    for (int r = 0; r < 4; ++r) {
                        const float v = (acc[i][j][r] + bj) * 0.125f;
                        const unsigned short hv = bf16_rtne(v);
                        const size_t idx = (hb * T_SEQ + tt + r) * HD + d;
                        Qh[idx] = (short)hv;
                        Ql[idx] = (short)bf16_rtne(v - bf16_tof(hv));
                    }
                } else if (region == 1) {
#pragma unroll
                    for (int r = 0; r < 4; ++r) {
                        const float v = acc[i][j][r] + bj;
                        Kb[(hb * T_SEQ + tt + r) * HD + d] = (short)bf16_rtne(v);
                    }
                } else {
                    s16x4 pv;
#pragma unroll
                    for (int r = 0; r < 4; ++r) pv[r] = (short)bf16_rtne(acc[i][j][r] + bj);
                    *(s16x4*)&Vt[(hb * HD + d) * T_SEQ + tt] = pv;
                }
            }
        }
    }
}

// ---------------------------------------------------------------------------
// Flash attention (causal) on pre-split bf16 Q/K/V.  One block = (b,h,64-q
// tile), 4 waves, wave w owns q-strip [16w,16w+16).  S^T = K @ Q^T (Q hi/lo
// 2-term, Q frags loaded straight from global).  In-register online softmax
// (shfl 16/32).  P[q][k] b64 writes.  PV: A=P, B=V^T (natural layout).
// Output written as hi/lo bf16 for the proj GEMM.
// ---------------------------------------------------------------------------
#define NEG_BIG (-3.402823466e+38f)

__global__ __launch_bounds__(256, 4) void flash_attn_bf16(
    const short* __restrict__ Qh, const short* __restrict__ Ql,
    const short* __restrict__ Kb, const short* __restrict__ Vt,
    short* __restrict__ yh, short* __restrict__ yl)
{
    __shared__ short Ks[64][72];
    __shared__ short Vs[64][72];
    __shared__ short Ps[64][72];
    __shared__ float redbuf[64];

    const int t = threadIdx.x;
    const int w = t >> 6;
    const int l = t & 63;
    const int c = l & 15;
    const int g = l >> 4;

    const int qt = gridDim.x - 1 - blockIdx.x;   // big tiles first
    const int bh = blockIdx.y;
    const int b  = bh / NH;
    const int hh = bh % NH;
    const int q0 = qt * 64;

    const size_t baseT = (size_t)bh * T_SEQ * HD;   // Q/K token-major base
    const size_t baseV = (size_t)bh * HD * T_SEQ;   // V^T base

    s16x8 qfh[2], qfl[2];
#pragma unroll
    for (int ds = 0; ds < 2; ++ds) {
        const size_t qi = baseT + (size_t)(q0 + 16 * w + c) * HD + ds * 32 + g * 8;
        qfh[ds] = *(const s16x8*)&Qh[qi];
        qfl[ds] = *(const s16x8*)&Ql[qi];
    }

    f32x4 o[4];
#pragma unroll
    for (int j = 0; j < 4; ++j) o[j] = (f32x4){0.f, 0.f, 0.f, 0.f};
    float m_run = NEG_BIG, l_run = 0.0f;

    for (int kt = 0; kt <= qt; ++kt) {
        const int k0 = kt * 64;
#pragma unroll
        for (int i = 0; i < 2; ++i) {
            const int chunk = t + i * 256;
            const int row   = chunk >> 3;
            const int col8  = (chunk & 7) * 8;
            *(s16x8*)&Ks[row][col8] = *(const s16x8*)&Kb[baseT + (size_t)(k0 + row) * HD + col8];
            *(s16x8*)&Vs[row][col8] = *(const s16x8*)&Vt[baseV + (size_t)row * T_SEQ + k0 + col8];
        }
        __syncthreads();

        f32x4 s[4];
#pragma unroll
        for (int sm = 0; sm < 4; ++sm) {
            s[sm] = (f32x4){0.f, 0.f, 0.f, 0.f};
#pragma unroll
            for (int ds = 0; ds < 2; ++ds) {
                const s16x8 kf = *(const s16x8*)&Ks[sm * 16 + c][ds * 32 + g * 8];
                s[sm] = __builtin_amdgcn_mfma_f32_16x16x32_bf16(kf, qfh[ds], s[sm], 0, 0, 0);
                s[sm] = __builtin_amdgcn_mfma_f32_16x16x32_bf16(kf, qfl[ds], s[sm], 0, 0, 0);
            }
        }

        if (kt == qt) {
            const int ql_ = 16 * w + c;
#pragma unroll
            for (int sm = 0; sm < 4; ++sm)
#pragma unroll
                for (int r = 0; r < 4; ++r)
                    if (16 * sm + 4 * g + r > ql_) s[sm][r] = NEG_BIG;
        }

        float mt = NEG_BIG;
#pragma unroll
        for (int sm = 0; sm < 4; ++sm)
#pragma unroll
            for (int r = 0; r < 4; ++r) mt = fmaxf(mt, s[sm][r]);
        mt = fmaxf(mt, __shfl_xor(mt, 16));
        mt = fmaxf(mt, __shfl_xor(mt, 32));
        const float mn    = fmaxf(m_run, mt);
        const float alpha = __expf(m_run - mn);
        m_run = mn;

        float ls = 0.0f;
#pragma unroll
        for (int sm = 0; sm < 4; ++sm)
#pragma unroll
            for (int r = 0; r < 4; ++r) {
                s[sm][r] = __expf(s[sm][r] - mn);
                ls += s[sm][r];
            }
        ls += __shfl_xor(ls, 16);
        ls += __shfl_xor(ls, 32);
        l_run = l_run * alpha + ls;

        if (g == 0) redbuf[16 * w + c] = alpha;

#pragma unroll
        for (int sm = 0; sm < 4; ++sm)
            *(s16x4*)&Ps[16 * w + c][sm * 16 + g * 4] =
                (s16x4){(short)bf16_rtne(s[sm][0]), (short)bf16_rtne(s[sm][1]),
                        (short)bf16_rtne(s[sm][2]), (short)bf16_rtne(s[sm][3])};

        {
            float av[4];
#pragma unroll
            for (int r = 0; r < 4; ++r) av[r] = redbuf[16 * w + 4 * g + r];
#pragma unroll
            for (int j = 0; j < 4; ++j)
#pragma unroll
                for (int r = 0; r < 4; ++r) o[j][r] *= av[r];
        }

#pragma unroll
        for (int ks = 0; ks < 2; ++ks) {
            const s16x8 pf = *(const s16x8*)&Ps[16 * w + c][ks * 32 + g * 8];
#pragma unroll
            for (int j = 0; j < 4; ++j) {
                const s16x8 vf = *(const s16x8*)&Vs[16 * j + c][ks * 32 + g * 8];
                o[j] = __builtin_amdgcn_mfma_f32_16x16x32_bf16(pf, vf, o[j], 0, 0, 0);
            }
        }
        __syncthreads();
    }

    if (g == 0) redbuf[16 * w + c] = l_run;
    float linv[4];
#pragma unroll
    for (int r = 0; r < 4; ++r) linv[r] = 1.0f / redbuf[16 * w + 4 * g + r];
#pragma unroll
    for (int j = 0; j < 4; ++j)
#pragma unroll
        for (int r = 0; r < 4; ++r) {
            const float ov = o[j][r] * linv[r];
            const unsigned short hv = bf16_rtne(ov);
            const size_t idx = ((size_t)b * T_SEQ + q0 + 16 * w + 4 * g + r) * C_DIM
                               + hh * HD + 16 * j + c;
            yh[idx] = (short)hv;
            yl[idx] = (short)bf16_rtne(ov - bf16_tof(hv));
        }
}

// ---------------------------------------------------------------------------
extern "C" void kernel_launch(void* const* d_in, const int* in_sizes, int n_in,
                              void* d_out, int out_size, void* d_ws, size_t ws_size,
                              hipStream_t stream)
{
    (void)in_sizes; (void)n_in; (void)out_size; (void)ws_size;
    const float* x      = (const float*)d_in[0];
    const float* W_attn = (const float*)d_in[1];
    const float* b_attn = (const float*)d_in[2];
    const float* W_proj = (const float*)d_in[3];
    const float* b_proj = (const float*)d_in[4];
    float* out = (float*)d_out;

    const size_t SX  = (size_t)BT * C_DIM;      // 6291456
    const size_t SWA = (size_t)C3 * C_DIM;      // 1769472
    const size_t SWP = (size_t)C_DIM * C_DIM;   // 589824

    short* p   = (short*)d_ws;
    short* xh  = p;            p += SX;
    short* xl  = p;            p += SX;
    short* Wah = p;            p += SWA;
    short* Wal = p;            p += SWA;
    short* Wph = p;            p += SWP;
    short* Wpl = p;            p += SWP;
    short* Qh  = p;            p += SX;
    short* Ql  = p;            p += SX;
    short* Kb  = p;            p += SX;
    short* Vt  = p;            p += SX;
    short* yh  = xh;           // alias: x dead after gemm1
    short* yl  = xl;

    split_bf16<<<1024, 256, 0, stream>>>(x,      xh,  xl,  (int)(SX  / 4));
    split_bf16<<<512,  256, 0, stream>>>(W_attn, Wah, Wal, (int)(SWA / 4));
    split_bf16<<<256,  256, 0, stream>>>(W_proj, Wph, Wpl, (int)(SWP / 4));

    gemm_bt_bf16<1><<<dim3(C3 / 128, BT / 128), 256, 0, stream>>>(
        xh, xl, Wah, Wal, b_attn, nullptr, Qh, Ql, Kb, Vt, BT, C3, C_DIM);

    flash_attn_bf16<<<dim3(T_SEQ / 64, 4 * NH), 256, 0, stream>>>(Qh, Ql, Kb, Vt, yh, yl);

    gemm_bt_bf16<0><<<dim3(C_DIM / 128, BT / 128), 256, 0, stream>>>(
        yh, yl, Wph, Wpl, b_proj, out, nullptr, nullptr, nullptr, nullptr, BT, C_DIM, C_DIM);
}

// Round 12
// 406.303 us; speedup vs baseline: 2.8233x; 1.0416x over previous
//
#include <hip/hip_runtime.h>
#include <cstdint>

#define T_SEQ 2048
#define C_DIM 768
#define C3    2304
#define NH    12
#define HD    64
#define BT    8192            // B*T

typedef float f32x4 __attribute__((ext_vector_type(4)));
typedef short s16x8 __attribute__((ext_vector_type(8)));
typedef short s16x4 __attribute__((ext_vector_type(4)));

__device__ __forceinline__ unsigned short bf16_rtne(float x) {
    union { float f; unsigned u; } v; v.f = x;
    unsigned r = (v.u + 0x7FFFu + ((v.u >> 16) & 1u)) >> 16;
    return (unsigned short)r;
}
__device__ __forceinline__ float bf16_tof(unsigned short h) {
    union { float f; unsigned u; } v; v.u = ((unsigned)h) << 16;
    return v.f;
}

// ---------------------------------------------------------------------------
// Elementwise fp32 -> (hi, lo) bf16 split. Runs once per input array.
// ---------------------------------------------------------------------------
__global__ __launch_bounds__(256) void split_bf16(const float* __restrict__ in,
                                                  short* __restrict__ hi,
                                                  short* __restrict__ lo, int n4)
{
    for (int i = blockIdx.x * blockDim.x + threadIdx.x; i < n4; i += gridDim.x * blockDim.x) {
        const float4 v = *(const float4*)&in[(size_t)i * 4];
        unsigned short h0 = bf16_rtne(v.x), h1 = bf16_rtne(v.y),
                       h2 = bf16_rtne(v.z), h3 = bf16_rtne(v.w);
        *(s16x4*)&hi[(size_t)i * 4] = (s16x4){(short)h0, (short)h1, (short)h2, (short)h3};
        *(s16x4*)&lo[(size_t)i * 4] = (s16x4){(short)bf16_rtne(v.x - bf16_tof(h0)),
                                              (short)bf16_rtne(v.y - bf16_tof(h1)),
                                              (short)bf16_rtne(v.z - bf16_tof(h2)),
                                              (short)bf16_rtne(v.w - bf16_tof(h3))};
    }
}

// ---------------------------------------------------------------------------
// Split-bf16 MFMA GEMM on pre-split operands.  (unchanged, measured-good)
// C[M,N] = (Ah+Al)[M,K] @ (Bh+Bl)[N,K]^T + bias[N]  (3-term split)
// Tile 128x128, BK=32, 256 thr = 4 waves (2x2), wave tile 64x64 (4x4 frags).
// MODE 0: f32 C out.  MODE 1: QKV epilogue -> Qh/Ql (scaled), K bf16, V^T bf16.
// ---------------------------------------------------------------------------
template<int MODE>
__global__ __launch_bounds__(256, 4) void gemm_bt_bf16(
    const short* __restrict__ Ah_g, const short* __restrict__ Al_g,
    const short* __restrict__ Bh_g, const short* __restrict__ Bl_g,
    const float* __restrict__ bias, float* __restrict__ Cout,
    short* __restrict__ Qh, short* __restrict__ Ql,
    short* __restrict__ Kb, short* __restrict__ Vt,
    int M, int N, int K)
{
    __shared__ short Ah[128][40];
    __shared__ short Al[128][40];
    __shared__ short Bh[128][40];
    __shared__ short Bl[128][40];

    const int t    = threadIdx.x;
    const int w    = t >> 6;
    const int lane = t & 63;
    const int lr   = lane & 15;
    const int g    = lane >> 4;
    const int lk   = g * 8;
    const int m0   = blockIdx.y * 128;
    const int n0   = blockIdx.x * 128;
    const int wm   = (w >> 1) * 64;
    const int wn   = (w & 1) * 64;

    f32x4 acc[4][4];
#pragma unroll
    for (int i = 0; i < 4; ++i)
#pragma unroll
        for (int j = 0; j < 4; ++j) acc[i][j] = (f32x4){0.f, 0.f, 0.f, 0.f};

    for (int kk = 0; kk < K; kk += 32) {
#pragma unroll
        for (int i = 0; i < 2; ++i) {
            const int chunk = t + i * 256;        // 512 x 16B chunks per tile
            const int row   = chunk >> 2;         // 0..127
            const int col8  = (chunk & 3) * 8;    // 0,8,16,24
            const size_t ga = (size_t)(m0 + row) * K + kk + col8;
            const size_t gb = (size_t)(n0 + row) * K + kk + col8;
            *(s16x8*)&Ah[row][col8] = *(const s16x8*)&Ah_g[ga];
            *(s16x8*)&Al[row][col8] = *(const s16x8*)&Al_g[ga];
            *(s16x8*)&Bh[row][col8] = *(const s16x8*)&Bh_g[gb];
            *(s16x8*)&Bl[row][col8] = *(const s16x8*)&Bl_g[gb];
        }
        __syncthreads();

        s16x8 afh[4], afl[4];
#pragma unroll
        for (int i = 0; i < 4; ++i) {
            afh[i] = *(const s16x8*)&Ah[wm + i * 16 + lr][lk];
            afl[i] = *(const s16x8*)&Al[wm + i * 16 + lr][lk];
        }
#pragma unroll
        for (int j = 0; j < 4; ++j) {
            const s16x8 bfh = *(const s16x8*)&Bh[wn + j * 16 + lr][lk];
            const s16x8 bfl = *(const s16x8*)&Bl[wn + j * 16 + lr][lk];
#pragma unroll
            for (int i = 0; i < 4; ++i) {
                acc[i][j] = __builtin_amdgcn_mfma_f32_16x16x32_bf16(afh[i], bfh, acc[i][j], 0, 0, 0);
                acc[i][j] = __builtin_amdgcn_mfma_f32_16x16x32_bf16(afh[i], bfl, acc[i][j], 0, 0, 0);
                acc[i][j] = __builtin_amdgcn_mfma_f32_16x16x32_bf16(afl[i], bfh, acc[i][j], 0, 0, 0);
            }
        }
        __syncthreads();
    }

    if (MODE == 0) {
#pragma unroll
        for (int j = 0; j < 4; ++j) {
            const float bj = bias[n0 + wn + j * 16 + lr];
#pragma unroll
            for (int i = 0; i < 4; ++i)
#pragma unroll
                for (int r = 0; r < 4; ++r) {
                    const int row = m0 + wm + i * 16 + g * 4 + r;
                    Cout[(size_t)row * N + n0 + wn + j * 16 + lr] = acc[i][j][r] + bj;
                }
        }
    } else {
        // QKV epilogue. Whole block is in one region (128-tiles don't straddle 768s).
        const int region = n0 / C_DIM;            // 0=Q, 1=K, 2=V
#pragma unroll
        for (int j = 0; j < 4; ++j) {
            const int n    = n0 + wn + j * 16 + lr;
            const float bj = bias[n];
            const int nr   = n - region * C_DIM;
            const int hh   = nr >> 6;             // head
            const int d    = nr & 63;
#pragma unroll
            for (int i = 0; i < 4; ++i) {
                const int rowb = m0 + wm + i * 16 + g * 4;
                const int b    = rowb >> 11;
                const int tt   = rowb & 2047;
                const size_t hb = (size_t)b * NH + hh;
                if (region == 0) {
#pragma unroll
                    for (int r = 0; r < 4; ++r) {
                        const float v = (acc[i][j][r] + bj) * 0.125f;
                        const unsigned short hv = bf16_rtne(v);
                        const size_t idx = (hb * T_SEQ + tt + r) * HD + d;
                        Qh[idx] = (short)hv;
                        Ql[idx] = (short)bf16_rtne(v - bf16_tof(hv));
                    }
                } else if (region == 1) {
#pragma unroll
                    for (int r = 0; r < 4; ++r) {
                        const float v = acc[i][j][r] + bj;
                        Kb[(hb * T_SEQ + tt + r) * HD + d] = (short)bf16_rtne(v);
                    }
                } else {
                    s16x4 pv;
#pragma unroll
                    for (int r = 0; r < 4; ++r) pv[r] = (short)bf16_rtne(acc[i][j][r] + bj);
                    *(s16x4*)&Vt[(hb * HD + d) * T_SEQ + tt] = pv;
                }
            }
        }
    }
}

// ---------------------------------------------------------------------------
// Flash attention (causal), 128-q blocks x 8 waves (512 threads).
// Staged K[64][72] / V^T[64][72] shared by 8 waves (2x the consumers per
// staged tile vs the 64-q version); per-wave compute identical to the
// measured-good 4-wave kernel (wave w owns q-strip 16w..16w+15, S^T = K@Q^T,
// in-register online softmax, P[q][k] -> LDS, PV with V^T).
// LDS 37.4 KB -> 4 blocks/CU = 2048 thr/CU (full).  VGPR ~48 <= 64 budget.
// ---------------------------------------------------------------------------
#define NEG_BIG (-3.402823466e+38f)

__global__ __launch_bounds__(512, 8) void flash_attn_bf16(
    const short* __restrict__ Qh, const short* __restrict__ Ql,
    const short* __restrict__ Kb, const short* __restrict__ Vt,
    short* __restrict__ yh, short* __restrict__ yl)
{
    __shared__ short Ks[64][72];
    __shared__ short Vs[64][72];
    __shared__ short Ps[128][72];
    __shared__ float redbuf[128];

    const int t = threadIdx.x;
    const int w = t >> 6;          // 0..7
    const int l = t & 63;
    const int c = l & 15;
    const int g = l >> 4;

    const int qt = gridDim.x - 1 - blockIdx.x;   // big tiles first
    const int bh = blockIdx.y;
    const int b  = bh / NH;
    const int hh = bh % NH;
    const int q0 = qt * 128;
    const int qwave = q0 + 16 * w;               // wave's lowest q row

    const size_t baseT = (size_t)bh * T_SEQ * HD;   // Q/K token-major base
    const size_t baseV = (size_t)bh * HD * T_SEQ;   // V^T base

    s16x8 qfh[2], qfl[2];
#pragma unroll
    for (int ds = 0; ds < 2; ++ds) {
        const size_t qi = baseT + (size_t)(qwave + c) * HD + ds * 32 + g * 8;
        qfh[ds] = *(const s16x8*)&Qh[qi];
        qfl[ds] = *(const s16x8*)&Ql[qi];
    }

    f32x4 o[4];
#pragma unroll
    for (int j = 0; j < 4; ++j) o[j] = (f32x4){0.f, 0.f, 0.f, 0.f};
    float m_run = NEG_BIG, l_run = 0.0f;

    const int nkt = (q0 + 128) / 64;             // k-tiles for this block
    for (int kt = 0; kt < nkt; ++kt) {
        const int k0 = kt * 64;
        // stage K [k][d] and V^T [d][k]: 512 threads, 1 chunk (16B) each
        {
            const int row  = t >> 3;             // 0..63
            const int col8 = (t & 7) * 8;        // 0..56
            *(s16x8*)&Ks[row][col8] = *(const s16x8*)&Kb[baseT + (size_t)(k0 + row) * HD + col8];
            *(s16x8*)&Vs[row][col8] = *(const s16x8*)&Vt[baseV + (size_t)row * T_SEQ + k0 + col8];
        }
        __syncthreads();

        if (k0 <= qwave + 15) {   // wave-uniform: skip all-masked tiles (no barrier inside)
            f32x4 s[4];
#pragma unroll
            for (int sm = 0; sm < 4; ++sm) {
                s[sm] = (f32x4){0.f, 0.f, 0.f, 0.f};
#pragma unroll
                for (int ds = 0; ds < 2; ++ds) {
                    const s16x8 kf = *(const s16x8*)&Ks[sm * 16 + c][ds * 32 + g * 8];
                    s[sm] = __builtin_amdgcn_mfma_f32_16x16x32_bf16(kf, qfh[ds], s[sm], 0, 0, 0);
                    s[sm] = __builtin_amdgcn_mfma_f32_16x16x32_bf16(kf, qfl[ds], s[sm], 0, 0, 0);
                }
            }

            if (k0 + 63 > qwave) {               // causal mask (wave-uniform guard)
                const int qg = qwave + c;
#pragma unroll
                for (int sm = 0; sm < 4; ++sm)
#pragma unroll
                    for (int r = 0; r < 4; ++r)
                        if (k0 + 16 * sm + 4 * g + r > qg) s[sm][r] = NEG_BIG;
            }

            float mt = NEG_BIG;
#pragma unroll
            for (int sm = 0; sm < 4; ++sm)
#pragma unroll
                for (int r = 0; r < 4; ++r) mt = fmaxf(mt, s[sm][r]);
            mt = fmaxf(mt, __shfl_xor(mt, 16));
            mt = fmaxf(mt, __shfl_xor(mt, 32));
            const float mn    = fmaxf(m_run, mt);
            const float alpha = __expf(m_run - mn);
            m_run = mn;

            float ls = 0.0f;
#pragma unroll
            for (int sm = 0; sm < 4; ++sm)
#pragma unroll
                for (int r = 0; r < 4; ++r) {
                    s[sm][r] = __expf(s[sm][r] - mn);
                    ls += s[sm][r];
                }
            ls += __shfl_xor(ls, 16);
            ls += __shfl_xor(ls, 32);
            l_run = l_run * alpha + ls;

            if (g == 0) redbuf[16 * w + c] = alpha;

#pragma unroll
            for (int sm = 0; sm < 4; ++sm)
                *(s16x4*)&Ps[16 * w + c][sm * 16 + g * 4] =
                    (s16x4){(short)bf16_rtne(s[sm][0]), (short)bf16_rtne(s[sm][1]),
                            (short)bf16_rtne(s[sm][2]), (short)bf16_rtne(s[sm][3])};

            {
                float av[4];
#pragma unroll
                for (int r = 0; r < 4; ++r) av[r] = redbuf[16 * w + 4 * g + r];
#pragma unroll
                for (int j = 0; j < 4; ++j)
#pragma unroll
                    for (int r = 0; r < 4; ++r) o[j][r] *= av[r];
            }

#pragma unroll
            for (int ks = 0; ks < 2; ++ks) {
                const s16x8 pf = *(const s16x8*)&Ps[16 * w + c][ks * 32 + g * 8];
#pragma unroll
                for (int j = 0; j < 4; ++j) {
                    const s16x8 vf = *(const s16x8*)&Vs[16 * j + c][ks * 32 + g * 8];
                    o[j] = __builtin_amdgcn_mfma_f32_16x16x32_bf16(pf, vf, o[j], 0, 0, 0);
                }
            }
        }
        __syncthreads();   // before next k-tile overwrites Ks/Vs
    }

    if (g == 0) redbuf[16 * w + c] = l_run;
    float linv[4];
#pragma unroll
    for (int r = 0; r < 4; ++r) linv[r] = 1.0f / redbuf[16 * w + 4 * g + r];
#pragma unroll
    for (int j = 0; j < 4; ++j)
#pragma unroll
        for (int r = 0; r < 4; ++r) {
            const float ov = o[j][r] * linv[r];
            const unsigned short hv = bf16_rtne(ov);
            const size_t idx = ((size_t)b * T_SEQ + qwave + 4 * g + r) * C_DIM
                               + hh * HD + 16 * j + c;
            yh[idx] = (short)hv;
            yl[idx] = (short)bf16_rtne(ov - bf16_tof(hv));
        }
}

// ---------------------------------------------------------------------------
extern "C" void kernel_launch(void* const* d_in, const int* in_sizes, int n_in,
                              void* d_out, int out_size, void* d_ws, size_t ws_size,
                              hipStream_t stream)
{
    (void)in_sizes; (void)n_in; (void)out_size; (void)ws_size;
    const float* x      = (const float*)d_in[0];
    const float* W_attn = (const float*)d_in[1];
    const float* b_attn = (const float*)d_in[2];
    const float* W_proj = (const float*)d_in[3];
    const float* b_proj = (const float*)d_in[4];
    float* out = (float*)d_out;

    const size_t SX  = (size_t)BT * C_DIM;      // 6291456
    const size_t SWA = (size_t)C3 * C_DIM;      // 1769472
    const size_t SWP = (size_t)C_DIM * C_DIM;   // 589824

    short* p   = (short*)d_ws;
    short* xh  = p;            p += SX;
    short* xl  = p;            p += SX;
    short* Wah = p;            p += SWA;
    short* Wal = p;            p += SWA;
    short* Wph = p;            p += SWP;
    short* Wpl = p;            p += SWP;
    short* Qh  = p;            p += SX;
    short* Ql  = p;            p += SX;
    short* Kb  = p;            p += SX;
    short* Vt  = p;            p += SX;
    short* yh  = xh;           // alias: x dead after gemm1
    short* yl  = xl;

    split_bf16<<<1024, 256, 0, stream>>>(x,      xh,  xl,  (int)(SX  / 4));
    split_bf16<<<512,  256, 0, stream>>>(W_attn, Wah, Wal, (int)(SWA / 4));
    split_bf16<<<256,  256, 0, stream>>>(W_proj, Wph, Wpl, (int)(SWP / 4));

    gemm_bt_bf16<1><<<dim3(C3 / 128, BT / 128), 256, 0, stream>>>(
        xh, xl, Wah, Wal, b_attn, nullptr, Qh, Ql, Kb, Vt, BT, C3, C_DIM);

    flash_attn_bf16<<<dim3(T_SEQ / 128, 4 * NH), 512, 0, stream>>>(Qh, Ql, Kb, Vt, yh, yl);

    gemm_bt_bf16<0><<<dim3(C_DIM / 128, BT / 128), 256, 0, stream>>>(
        yh, yl, Wph, Wpl, b_proj, out, nullptr, nullptr, nullptr, nullptr, BT, C_DIM, C_DIM);
}